// Round 8
// baseline (141.442 us; speedup 1.0000x reference)
//
#include <hip/hip_runtime.h>

// Point-transformer block. R7 = R6 + phase-3 MLP distributed across all
// 4 waves (12-input partials per wave, LDS combine), DPP+readlane final
// reduce, and __builtin_elementwise_max for guaranteed v_pk_max_f16.
// One block per group (B*G = 16384), 256 threads = one per (i,j) pair.

typedef _Float16 h2 __attribute__((ext_vector_type(2)));
typedef _Float16 h8 __attribute__((ext_vector_type(8)));

#define AH_STRIDE 36   // a-table row stride in dwords (32 data + 4 pad)

union H8U { h8 v; h2 p[4]; unsigned u[4]; };

__device__ __forceinline__ h2 pkrtz(float a, float b) {
    return __builtin_bit_cast(h2, __builtin_amdgcn_cvt_pkrtz(a, b));
}
__device__ __forceinline__ h2 uash2(unsigned u) {
    return __builtin_bit_cast(h2, u);
}
__device__ __forceinline__ h2 hmax2(h2 a, h2 b) {
    return __builtin_elementwise_max(a, b);   // v_pk_max_f16
}

#if __has_builtin(__builtin_amdgcn_fdot2)
__device__ __forceinline__ float dot2acc(h2 a, h2 b, float c) {
    return __builtin_amdgcn_fdot2(a, b, c, false);
}
#else
__device__ __forceinline__ float dot2acc(h2 a, h2 b, float c) {
    return fmaf((float)a.x, (float)b.x, fmaf((float)a.y, (float)b.y, c));
}
#endif

// sum across the 16-lane DPP row via row_ror 1,2,4,8 (all lanes get total)
__device__ __forceinline__ float dpp_add16(float x) {
    float s = x;
    int t;
    t = __builtin_amdgcn_update_dpp(0, __builtin_bit_cast(int, s), 0x121, 0xf, 0xf, false);
    s += __builtin_bit_cast(float, t);
    t = __builtin_amdgcn_update_dpp(0, __builtin_bit_cast(int, s), 0x122, 0xf, 0xf, false);
    s += __builtin_bit_cast(float, t);
    t = __builtin_amdgcn_update_dpp(0, __builtin_bit_cast(int, s), 0x124, 0xf, 0xf, false);
    s += __builtin_bit_cast(float, t);
    t = __builtin_amdgcn_update_dpp(0, __builtin_bit_cast(int, s), 0x128, 0xf, 0xf, false);
    s += __builtin_bit_cast(float, t);
    return s;
}

// ---- pre-kernel: pack f16-pair weight tables into workspace ----
__global__ void wpack(const float* __restrict__ pw2, const float* __restrict__ aw1,
                      const float* __restrict__ ab1, const float* __restrict__ aw2,
                      unsigned* __restrict__ ws) {
    const int t = threadIdx.x;
    if (t < 96) {
        const int hp = t & 31, c = t >> 5;
        ws[c*32+hp] = __builtin_bit_cast(unsigned, pkrtz(pw2[(2*hp)*3+c], pw2[(2*hp+1)*3+c]));
    } else if (t < 114) {
        const int idx = t - 96, r = idx / 6, gp = idx % 6;
        ws[96+r*6+gp] = __builtin_bit_cast(unsigned, pkrtz(aw1[r*12+2*gp], aw1[r*12+2*gp+1]));
    } else if (t < 120) {
        const int gp = t - 114;
        ws[114+gp] = __builtin_bit_cast(unsigned, pkrtz(ab1[2*gp], ab1[2*gp+1]));
    } else if (t < 138) {
        const int idx = t - 120, gp = idx / 3, c = idx % 3;
        ws[120+gp*3+c] = __builtin_bit_cast(unsigned, pkrtz(aw2[(2*gp)*3+c], aw2[(2*gp+1)*3+c]));
    }
}

__global__ __launch_bounds__(256) void pt_main(
    const float* __restrict__ data,     // (BG, 16, 3)
    const float* __restrict__ wqkv,     // (3, 9)
    const float* __restrict__ pw1,      // (3, 64)
    const float* __restrict__ pb1,      // (64)
    const float* __restrict__ pb2,      // (3)
    const float* __restrict__ ab2,      // (3)
    const float* __restrict__ mw1,      // (48, 48)
    const float* __restrict__ mb1,      // (48)
    const float* __restrict__ mw2,      // (48, 48)
    const float* __restrict__ mb2,      // (48)
    const float* __restrict__ mw3,      // (48, 1)
    const float* __restrict__ mb3,      // (1)
    const unsigned* __restrict__ wsp,   // packed f16-pair weights (uniform -> s_load)
    float* __restrict__ out)            // (BG)
{
    __shared__ __attribute__((aligned(16))) float s_pos[48];
    __shared__ __attribute__((aligned(16))) float s_q4[64], s_k4[64], s_v4[64];
    __shared__ __attribute__((aligned(16))) float s_sa[48], s_h1[48];
    __shared__ __attribute__((aligned(16))) float s_p[4 * 48];          // MLP partials
    __shared__ __attribute__((aligned(16))) unsigned s_a1h[16 * AH_STRIDE];
    __shared__ __attribute__((aligned(16))) unsigned s_a2h[16 * AH_STRIDE];

    const int g = blockIdx.x;
    const int t = threadIdx.x;
    const int wv = t >> 6;
    const int o  = t & 63;      // lane

    // ---- phase 0: load the 16 points (48 floats) ----
    if (t < 48) s_pos[t] = data[g * 48 + t];
    __syncthreads();

    // ---- phase 1a: qkv (threads 0..47), stride-4 layout ----
    if (t < 48) {
        const int sec = t >> 4, p = t & 15;
        const float x0 = s_pos[p*3+0], x1 = s_pos[p*3+1], x2 = s_pos[p*3+2];
        float* dst = (sec == 0) ? s_q4 : (sec == 1) ? s_k4 : s_v4;
        #pragma unroll
        for (int c = 0; c < 3; ++c) {
            dst[p*4+c] = fmaf(x0, wqkv[0*9 + sec*3 + c],
                         fmaf(x1, wqkv[1*9 + sec*3 + c],
                         x2 * wqkv[2*9 + sec*3 + c]));
        }
        dst[p*4+3] = 0.0f;
    }

    // ---- phase 1b: a-tables in packed f16. thread -> point t>>4, 4 h ----
    {
        const int ii = t >> 4;
        const int hc = (t & 15) << 2;
        const float x0 = s_pos[ii*3+0], x1 = s_pos[ii*3+1], x2 = s_pos[ii*3+2];
        float s[4];
        #pragma unroll
        for (int c = 0; c < 4; ++c) {
            const int h = hc + c;
            s[c] = fmaf(x0, pw1[h], fmaf(x1, pw1[64+h], x2 * pw1[128+h]));
        }
        h2 a1p0 = pkrtz(s[0] + pb1[hc+0], s[1] + pb1[hc+1]);
        h2 a1p1 = pkrtz(s[2] + pb1[hc+2], s[3] + pb1[hc+3]);
        h2 a2p0 = pkrtz(s[0], s[1]);
        h2 a2p1 = pkrtz(s[2], s[3]);
        const int base = ii * AH_STRIDE + (hc >> 1);
        s_a1h[base+0] = __builtin_bit_cast(unsigned, a1p0);
        s_a1h[base+1] = __builtin_bit_cast(unsigned, a1p1);
        s_a2h[base+0] = __builtin_bit_cast(unsigned, a2p0);
        s_a2h[base+1] = __builtin_bit_cast(unsigned, a2p1);
    }
    __syncthreads();

    // ---- phase 2: per-pair. i = t>>4, j = t&15 ----
    const int i = t >> 4, j = t & 15;

    float e0 = pb2[0], e1 = pb2[1], e2 = pb2[2];
    #pragma unroll
    for (int cc = 0; cc < 8; ++cc) {
        H8U ai, aj;
        ai.v = *(const h8*)&s_a1h[i * AH_STRIDE + cc*4];
        aj.v = *(const h8*)&s_a2h[j * AH_STRIDE + cc*4];
        #pragma unroll
        for (int m = 0; m < 4; ++m) {
            const int hp = cc*4 + m;
            h2 d = ai.p[m] - aj.p[m];
            h2 z = {(_Float16)0, (_Float16)0};
            h2 r = hmax2(d, z);
            e0 = dot2acc(r, uash2(wsp[0*32+hp]), e0);
            e1 = dot2acc(r, uash2(wsp[1*32+hp]), e1);
            e2 = dot2acc(r, uash2(wsp[2*32+hp]), e2);
        }
    }

    const float4 qv = *(const float4*)&s_q4[i*4];
    const float4 kv = *(const float4*)&s_k4[j*4];
    const float4 vv = *(const float4*)&s_v4[j*4];
    const float vi0 = vv.x + e0, vi1 = vv.y + e1, vi2 = vv.z + e2;
    const float si0 = qv.x - kv.x + e0;
    const float si1 = qv.y - kv.y + e1;
    const float si2 = qv.z - kv.z + e2;

    // attn-MLP in packed f16
    const h2 sx = pkrtz(si0, si0), sy = pkrtz(si1, si1), sz = pkrtz(si2, si2);
    const h2 z2 = {(_Float16)0, (_Float16)0};
    float m0 = ab2[0], m1 = ab2[1], m2 = ab2[2];
    #pragma unroll
    for (int gp = 0; gp < 6; ++gp) {
        h2 acc = uash2(wsp[114+gp]);
        acc = __builtin_elementwise_fma(sx, uash2(wsp[96+0*6+gp]), acc);
        acc = __builtin_elementwise_fma(sy, uash2(wsp[96+1*6+gp]), acc);
        acc = __builtin_elementwise_fma(sz, uash2(wsp[96+2*6+gp]), acc);
        h2 hg = hmax2(acc, z2);
        m0 = dot2acc(hg, uash2(wsp[120+gp*3+0]), m0);
        m1 = dot2acc(hg, uash2(wsp[120+gp*3+1]), m1);
        m2 = dot2acc(hg, uash2(wsp[120+gp*3+2]), m2);
    }

    // ---- softmax over j: DPP row sums, no max-subtraction ----
    const float L2E = 1.44269504f;
    const float p0 = __builtin_amdgcn_exp2f(m0 * L2E);
    const float p1 = __builtin_amdgcn_exp2f(m1 * L2E);
    const float p2 = __builtin_amdgcn_exp2f(m2 * L2E);

    const float n0 = dpp_add16(p0 * vi0);
    const float n1 = dpp_add16(p1 * vi1);
    const float n2 = dpp_add16(p2 * vi2);
    const float d0 = dpp_add16(p0);
    const float d1 = dpp_add16(p1);
    const float d2 = dpp_add16(p2);

    if (j == 0) {
        s_sa[i*3+0] = n0 * __builtin_amdgcn_rcpf(d0);
        s_sa[i*3+1] = n1 * __builtin_amdgcn_rcpf(d1);
        s_sa[i*3+2] = n2 * __builtin_amdgcn_rcpf(d2);
    }
    __syncthreads();

    // ---- phase 3: MLP 48->48->48->1, distributed over 4 waves ----
    // layer 1 partials: wave wv covers inputs [12wv, 12wv+12)
    if (o < 48) {
        const int c0 = wv * 12;
        const float4 sa0 = *(const float4*)&s_sa[c0];      // wave-uniform bcast
        const float4 sa1 = *(const float4*)&s_sa[c0 + 4];
        const float4 sa2 = *(const float4*)&s_sa[c0 + 8];
        float pa = 0.f, pb = 0.f;
        #pragma unroll
        for (int c = 0; c < 4; ++c) {
            pa = fmaf((&sa0.x)[c], mw1[(c0+c)*48+o], pa);
            pb = fmaf((&sa1.x)[c], mw1[(c0+4+c)*48+o], pb);
            pa = fmaf((&sa2.x)[c], mw1[(c0+8+c)*48+o], pa);
        }
        s_p[wv*48+o] = pa + pb;
    }
    __syncthreads();

    if (t < 48) {
        const float h1 = s_p[0*48+t] + s_p[1*48+t] + s_p[2*48+t] + s_p[3*48+t] + mb1[t];
        s_h1[t] = fmaxf(h1, 0.0f);
    }
    __syncthreads();

    // layer 2 partials
    if (o < 48) {
        const int c0 = wv * 12;
        const float4 hh0 = *(const float4*)&s_h1[c0];
        const float4 hh1 = *(const float4*)&s_h1[c0 + 4];
        const float4 hh2 = *(const float4*)&s_h1[c0 + 8];
        float pa = 0.f, pb = 0.f;
        #pragma unroll
        for (int c = 0; c < 4; ++c) {
            pa = fmaf((&hh0.x)[c], mw2[(c0+c)*48+o], pa);
            pb = fmaf((&hh1.x)[c], mw2[(c0+4+c)*48+o], pb);
            pa = fmaf((&hh2.x)[c], mw2[(c0+8+c)*48+o], pa);
        }
        s_p[wv*48+o] = pa + pb;
    }
    __syncthreads();

    // final: wave 0, lanes 0..47
    if (t < 64) {
        float fv = 0.0f;
        if (t < 48) {
            const float h2v = fmaxf(
                s_p[0*48+t] + s_p[1*48+t] + s_p[2*48+t] + s_p[3*48+t] + mb2[t], 0.0f);
            fv = h2v * mw3[t];
        }
        const float r = dpp_add16(fv);   // row sums in lanes 0,16,32
        const int ri = __builtin_bit_cast(int, r);
        const float tot =
            __builtin_bit_cast(float, __builtin_amdgcn_readlane(ri, 0)) +
            __builtin_bit_cast(float, __builtin_amdgcn_readlane(ri, 16)) +
            __builtin_bit_cast(float, __builtin_amdgcn_readlane(ri, 32));
        if (t == 0) out[g] = tot + mb3[0];
    }
}

extern "C" void kernel_launch(void* const* d_in, const int* in_sizes, int n_in,
                              void* d_out, int out_size, void* d_ws, size_t ws_size,
                              hipStream_t stream) {
    const float* data = (const float*)d_in[1];
    unsigned* ws = (unsigned*)d_ws;
    const int groups = out_size;  // B*G = 16384

    wpack<<<1, 256, 0, stream>>>(
        (const float*)d_in[5],   // pw2
        (const float*)d_in[7],   // aw1
        (const float*)d_in[8],   // ab1
        (const float*)d_in[9],   // aw2
        ws);

    pt_main<<<groups, 256, 0, stream>>>(
        data,
        (const float*)d_in[2],   // wqkv
        (const float*)d_in[3],   // pw1
        (const float*)d_in[4],   // pb1
        (const float*)d_in[6],   // pb2
        (const float*)d_in[10],  // ab2
        (const float*)d_in[11],  // mw1
        (const float*)d_in[12],  // mb1
        (const float*)d_in[13],  // mw2
        (const float*)d_in[14],  // mb2
        (const float*)d_in[15],  // mw3
        (const float*)d_in[16],  // mb3
        ws,
        (float*)d_out);
}

// Round 9
// 136.915 us; speedup vs baseline: 1.0331x; 1.0331x over previous
//
#include <hip/hip_runtime.h>

// Point-transformer block. R8 = R6 phase structure, but TWO groups per
// block (256 thr = 2 x 128), each thread owns pairs (i,j) and (i+8,j).
// Fixed costs (qkv, a-tables, barriers, phase-3 tail) amortized over 2
// groups; phase-3 runs per-group on waves 0 and 2 concurrently, no extra
// barriers. Positions read directly from global (s_pos stage deleted).

typedef _Float16 h2 __attribute__((ext_vector_type(2)));
typedef _Float16 h8 __attribute__((ext_vector_type(8)));

#define AH_STRIDE 36   // a-table row stride in dwords (32 data + 4 pad)

union H8U { h8 v; h2 p[4]; unsigned u[4]; };

__device__ __forceinline__ h2 pkrtz(float a, float b) {
    return __builtin_bit_cast(h2, __builtin_amdgcn_cvt_pkrtz(a, b));
}
__device__ __forceinline__ h2 uash2(unsigned u) {
    return __builtin_bit_cast(h2, u);
}
__device__ __forceinline__ h2 hmax2(h2 a, h2 b) {
    return __builtin_elementwise_max(a, b);   // v_pk_max_f16
}

#if __has_builtin(__builtin_amdgcn_fdot2)
__device__ __forceinline__ float dot2acc(h2 a, h2 b, float c) {
    return __builtin_amdgcn_fdot2(a, b, c, false);
}
#else
__device__ __forceinline__ float dot2acc(h2 a, h2 b, float c) {
    return fmaf((float)a.x, (float)b.x, fmaf((float)a.y, (float)b.y, c));
}
#endif

// sum across the 16-lane DPP row via row_ror 1,2,4,8 (all lanes get total)
__device__ __forceinline__ float dpp_add16(float x) {
    float s = x;
    int t;
    t = __builtin_amdgcn_update_dpp(0, __builtin_bit_cast(int, s), 0x121, 0xf, 0xf, false);
    s += __builtin_bit_cast(float, t);
    t = __builtin_amdgcn_update_dpp(0, __builtin_bit_cast(int, s), 0x122, 0xf, 0xf, false);
    s += __builtin_bit_cast(float, t);
    t = __builtin_amdgcn_update_dpp(0, __builtin_bit_cast(int, s), 0x124, 0xf, 0xf, false);
    s += __builtin_bit_cast(float, t);
    t = __builtin_amdgcn_update_dpp(0, __builtin_bit_cast(int, s), 0x128, 0xf, 0xf, false);
    s += __builtin_bit_cast(float, t);
    return s;
}

// ---- pre-kernel: pack f16-pair weight tables into workspace ----
__global__ void wpack(const float* __restrict__ pw2, const float* __restrict__ aw1,
                      const float* __restrict__ ab1, const float* __restrict__ aw2,
                      unsigned* __restrict__ ws) {
    const int t = threadIdx.x;
    if (t < 96) {
        const int hp = t & 31, c = t >> 5;
        ws[c*32+hp] = __builtin_bit_cast(unsigned, pkrtz(pw2[(2*hp)*3+c], pw2[(2*hp+1)*3+c]));
    } else if (t < 114) {
        const int idx = t - 96, r = idx / 6, gp = idx % 6;
        ws[96+r*6+gp] = __builtin_bit_cast(unsigned, pkrtz(aw1[r*12+2*gp], aw1[r*12+2*gp+1]));
    } else if (t < 120) {
        const int gp = t - 114;
        ws[114+gp] = __builtin_bit_cast(unsigned, pkrtz(ab1[2*gp], ab1[2*gp+1]));
    } else if (t < 138) {
        const int idx = t - 120, gp = idx / 3, c = idx % 3;
        ws[120+gp*3+c] = __builtin_bit_cast(unsigned, pkrtz(aw2[(2*gp)*3+c], aw2[(2*gp+1)*3+c]));
    }
}

__global__ __launch_bounds__(256) void pt_main(
    const float* __restrict__ data,     // (BG, 16, 3)
    const float* __restrict__ wqkv,     // (3, 9)
    const float* __restrict__ pw1,      // (3, 64)
    const float* __restrict__ pb1,      // (64)
    const float* __restrict__ pb2,      // (3)
    const float* __restrict__ ab2,      // (3)
    const float* __restrict__ mw1,      // (48, 48)
    const float* __restrict__ mb1,      // (48)
    const float* __restrict__ mw2,      // (48, 48)
    const float* __restrict__ mb2,      // (48)
    const float* __restrict__ mw3,      // (48, 1)
    const float* __restrict__ mb3,      // (1)
    const unsigned* __restrict__ wsp,   // packed f16-pair weights (uniform)
    float* __restrict__ out)            // (BG)
{
    __shared__ __attribute__((aligned(16))) float s_q4[2][64], s_k4[2][64], s_v4[2][64];
    __shared__ __attribute__((aligned(16))) float s_sa[2][48];
    __shared__ __attribute__((aligned(16))) float s_h1[2][48];
    __shared__ __attribute__((aligned(16))) unsigned s_a1h[2][16 * AH_STRIDE];
    __shared__ __attribute__((aligned(16))) unsigned s_a2h[2][16 * AH_STRIDE];

    const int t   = threadIdx.x;
    const int grp = t >> 7;            // group within block (0/1)
    const int lt  = t & 127;           // lane within group
    const int g   = blockIdx.x * 2 + grp;

    // ---- phase 1a: qkv (lt 0..47 per group), stride-4 layout ----
    if (lt < 48) {
        const int sec = lt >> 4, p = lt & 15;
        const float x0 = data[g*48 + p*3 + 0];
        const float x1 = data[g*48 + p*3 + 1];
        const float x2 = data[g*48 + p*3 + 2];
        float* dst = (sec == 0) ? s_q4[grp] : (sec == 1) ? s_k4[grp] : s_v4[grp];
        #pragma unroll
        for (int c = 0; c < 3; ++c) {
            dst[p*4+c] = fmaf(x0, wqkv[0*9 + sec*3 + c],
                         fmaf(x1, wqkv[1*9 + sec*3 + c],
                         x2 * wqkv[2*9 + sec*3 + c]));
        }
        dst[p*4+3] = 0.0f;
    }

    // ---- phase 1b: a-tables in packed f16. point = lt>>3, 8 hiddens ----
    {
        const int p  = lt >> 3;
        const int hc = (lt & 7) << 3;
        const float x0 = data[g*48 + p*3 + 0];
        const float x1 = data[g*48 + p*3 + 1];
        const float x2 = data[g*48 + p*3 + 2];
        const float4 w0a = *(const float4*)&pw1[hc],     w0b = *(const float4*)&pw1[hc+4];
        const float4 w1a = *(const float4*)&pw1[64+hc],  w1b = *(const float4*)&pw1[64+hc+4];
        const float4 w2a = *(const float4*)&pw1[128+hc], w2b = *(const float4*)&pw1[128+hc+4];
        const float4 ba  = *(const float4*)&pb1[hc],     bb  = *(const float4*)&pb1[hc+4];
        float s[8];
        #pragma unroll
        for (int c = 0; c < 4; ++c) {
            s[c]   = fmaf(x0, (&w0a.x)[c], fmaf(x1, (&w1a.x)[c], x2 * (&w2a.x)[c]));
            s[4+c] = fmaf(x0, (&w0b.x)[c], fmaf(x1, (&w1b.x)[c], x2 * (&w2b.x)[c]));
        }
        uint4 a1u, a2u;
        a1u.x = __builtin_bit_cast(unsigned, pkrtz(s[0]+ba.x, s[1]+ba.y));
        a1u.y = __builtin_bit_cast(unsigned, pkrtz(s[2]+ba.z, s[3]+ba.w));
        a1u.z = __builtin_bit_cast(unsigned, pkrtz(s[4]+bb.x, s[5]+bb.y));
        a1u.w = __builtin_bit_cast(unsigned, pkrtz(s[6]+bb.z, s[7]+bb.w));
        a2u.x = __builtin_bit_cast(unsigned, pkrtz(s[0], s[1]));
        a2u.y = __builtin_bit_cast(unsigned, pkrtz(s[2], s[3]));
        a2u.z = __builtin_bit_cast(unsigned, pkrtz(s[4], s[5]));
        a2u.w = __builtin_bit_cast(unsigned, pkrtz(s[6], s[7]));
        const int base = p * AH_STRIDE + (hc >> 1);
        *(uint4*)&s_a1h[grp][base] = a1u;
        *(uint4*)&s_a2h[grp][base] = a2u;
    }
    __syncthreads();

    // ---- phase 2: two pairs per thread: (i,j) and (i+8,j) ----
    const int i = lt >> 4, j = lt & 15, i2 = i + 8;

    float eA0 = pb2[0], eA1 = pb2[1], eA2 = pb2[2];
    float eB0 = pb2[0], eB1 = pb2[1], eB2 = pb2[2];
    #pragma unroll
    for (int cc = 0; cc < 8; ++cc) {
        H8U aiA, aiB, aj;
        aiA.v = *(const h8*)&s_a1h[grp][i  * AH_STRIDE + cc*4];
        aiB.v = *(const h8*)&s_a1h[grp][i2 * AH_STRIDE + cc*4];
        aj.v  = *(const h8*)&s_a2h[grp][j  * AH_STRIDE + cc*4];
        #pragma unroll
        for (int m = 0; m < 4; ++m) {
            const int hp = cc*4 + m;
            const h2 z = {(_Float16)0, (_Float16)0};
            const h2 w0 = uash2(wsp[0*32+hp]);
            const h2 w1 = uash2(wsp[1*32+hp]);
            const h2 w2 = uash2(wsp[2*32+hp]);
            h2 rA = hmax2(aiA.p[m] - aj.p[m], z);
            h2 rB = hmax2(aiB.p[m] - aj.p[m], z);
            eA0 = dot2acc(rA, w0, eA0);
            eA1 = dot2acc(rA, w1, eA1);
            eA2 = dot2acc(rA, w2, eA2);
            eB0 = dot2acc(rB, w0, eB0);
            eB1 = dot2acc(rB, w1, eB1);
            eB2 = dot2acc(rB, w2, eB2);
        }
    }

    const float4 qA = *(const float4*)&s_q4[grp][i*4];
    const float4 qB = *(const float4*)&s_q4[grp][i2*4];
    const float4 kv = *(const float4*)&s_k4[grp][j*4];
    const float4 vv = *(const float4*)&s_v4[grp][j*4];

    const float viA0 = vv.x + eA0, viA1 = vv.y + eA1, viA2 = vv.z + eA2;
    const float viB0 = vv.x + eB0, viB1 = vv.y + eB1, viB2 = vv.z + eB2;
    const float siA0 = qA.x - kv.x + eA0, siA1 = qA.y - kv.y + eA1, siA2 = qA.z - kv.z + eA2;
    const float siB0 = qB.x - kv.x + eB0, siB1 = qB.y - kv.y + eB1, siB2 = qB.z - kv.z + eB2;

    // attn-MLP in packed f16, both pairs
    const h2 z2 = {(_Float16)0, (_Float16)0};
    const h2 sAx = pkrtz(siA0, siA0), sAy = pkrtz(siA1, siA1), sAz = pkrtz(siA2, siA2);
    const h2 sBx = pkrtz(siB0, siB0), sBy = pkrtz(siB1, siB1), sBz = pkrtz(siB2, siB2);
    float mA0 = ab2[0], mA1 = ab2[1], mA2 = ab2[2];
    float mB0 = ab2[0], mB1 = ab2[1], mB2 = ab2[2];
    #pragma unroll
    for (int gp = 0; gp < 6; ++gp) {
        const h2 b1p = uash2(wsp[114+gp]);
        const h2 u0 = uash2(wsp[96+0*6+gp]);
        const h2 u1 = uash2(wsp[96+1*6+gp]);
        const h2 u2 = uash2(wsp[96+2*6+gp]);
        const h2 v0 = uash2(wsp[120+gp*3+0]);
        const h2 v1 = uash2(wsp[120+gp*3+1]);
        const h2 v2 = uash2(wsp[120+gp*3+2]);
        h2 accA = b1p, accB = b1p;
        accA = __builtin_elementwise_fma(sAx, u0, accA);
        accA = __builtin_elementwise_fma(sAy, u1, accA);
        accA = __builtin_elementwise_fma(sAz, u2, accA);
        accB = __builtin_elementwise_fma(sBx, u0, accB);
        accB = __builtin_elementwise_fma(sBy, u1, accB);
        accB = __builtin_elementwise_fma(sBz, u2, accB);
        h2 hA = hmax2(accA, z2), hB = hmax2(accB, z2);
        mA0 = dot2acc(hA, v0, mA0);
        mA1 = dot2acc(hA, v1, mA1);
        mA2 = dot2acc(hA, v2, mA2);
        mB0 = dot2acc(hB, v0, mB0);
        mB1 = dot2acc(hB, v1, mB1);
        mB2 = dot2acc(hB, v2, mB2);
    }

    // ---- softmax over j (DPP row sums), both pairs ----
    const float L2E = 1.44269504f;
    const float pA0 = __builtin_amdgcn_exp2f(mA0 * L2E);
    const float pA1 = __builtin_amdgcn_exp2f(mA1 * L2E);
    const float pA2 = __builtin_amdgcn_exp2f(mA2 * L2E);
    const float pB0 = __builtin_amdgcn_exp2f(mB0 * L2E);
    const float pB1 = __builtin_amdgcn_exp2f(mB1 * L2E);
    const float pB2 = __builtin_amdgcn_exp2f(mB2 * L2E);

    const float nA0 = dpp_add16(pA0 * viA0);
    const float nA1 = dpp_add16(pA1 * viA1);
    const float nA2 = dpp_add16(pA2 * viA2);
    const float dA0 = dpp_add16(pA0);
    const float dA1 = dpp_add16(pA1);
    const float dA2 = dpp_add16(pA2);
    const float nB0 = dpp_add16(pB0 * viB0);
    const float nB1 = dpp_add16(pB1 * viB1);
    const float nB2 = dpp_add16(pB2 * viB2);
    const float dB0 = dpp_add16(pB0);
    const float dB1 = dpp_add16(pB1);
    const float dB2 = dpp_add16(pB2);

    if (j == 0) {
        s_sa[grp][i*3+0]  = nA0 * __builtin_amdgcn_rcpf(dA0);
        s_sa[grp][i*3+1]  = nA1 * __builtin_amdgcn_rcpf(dA1);
        s_sa[grp][i*3+2]  = nA2 * __builtin_amdgcn_rcpf(dA2);
        s_sa[grp][i2*3+0] = nB0 * __builtin_amdgcn_rcpf(dB0);
        s_sa[grp][i2*3+1] = nB1 * __builtin_amdgcn_rcpf(dB1);
        s_sa[grp][i2*3+2] = nB2 * __builtin_amdgcn_rcpf(dB2);
    }
    __syncthreads();

    // ---- phase 3: MLP 48->48->48->1, group A on wave 0, group B on wave 2 ----
    if (lt < 48) {
        const int o = lt;
        // layer 1 (4-way ILP)
        float a0 = 0.f, a1 = 0.f, a2 = 0.f, a3 = 0.f;
        #pragma unroll
        for (int c = 0; c < 48; c += 4) {
            const float4 sa = *(const float4*)&s_sa[grp][c];
            a0 = fmaf(sa.x, mw1[(c+0)*48+o], a0);
            a1 = fmaf(sa.y, mw1[(c+1)*48+o], a1);
            a2 = fmaf(sa.z, mw1[(c+2)*48+o], a2);
            a3 = fmaf(sa.w, mw1[(c+3)*48+o], a3);
        }
        s_h1[grp][o] = fmaxf((a0+a1) + (a2+a3) + mb1[o], 0.0f);
        __builtin_amdgcn_wave_barrier();   // same-wave LDS handoff (in-order DS pipe)
        // layer 2 (4-way ILP)
        float b0 = 0.f, b1 = 0.f, b2 = 0.f, b3 = 0.f;
        #pragma unroll
        for (int c = 0; c < 48; c += 4) {
            const float4 hh = *(const float4*)&s_h1[grp][c];
            b0 = fmaf(hh.x, mw2[(c+0)*48+o], b0);
            b1 = fmaf(hh.y, mw2[(c+1)*48+o], b1);
            b2 = fmaf(hh.z, mw2[(c+2)*48+o], b2);
            b3 = fmaf(hh.w, mw2[(c+3)*48+o], b3);
        }
        const float h2v = fmaxf((b0+b1) + (b2+b3) + mb2[o], 0.0f);
        const float fv = h2v * mw3[o];
        const float r = dpp_add16(fv);     // row sums in lanes 0,16,32
        const int ri = __builtin_bit_cast(int, r);
        const float tot =
            __builtin_bit_cast(float, __builtin_amdgcn_readlane(ri, 0)) +
            __builtin_bit_cast(float, __builtin_amdgcn_readlane(ri, 16)) +
            __builtin_bit_cast(float, __builtin_amdgcn_readlane(ri, 32));
        if (o == 0) out[g] = tot + mb3[0];
    }
}

extern "C" void kernel_launch(void* const* d_in, const int* in_sizes, int n_in,
                              void* d_out, int out_size, void* d_ws, size_t ws_size,
                              hipStream_t stream) {
    const float* data = (const float*)d_in[1];
    unsigned* ws = (unsigned*)d_ws;
    const int groups = out_size;  // B*G = 16384

    wpack<<<1, 256, 0, stream>>>(
        (const float*)d_in[5],   // pw2
        (const float*)d_in[7],   // aw1
        (const float*)d_in[8],   // ab1
        (const float*)d_in[9],   // aw2
        ws);

    pt_main<<<groups / 2, 256, 0, stream>>>(
        data,
        (const float*)d_in[2],   // wqkv
        (const float*)d_in[3],   // pw1
        (const float*)d_in[4],   // pb1
        (const float*)d_in[6],   // pb2
        (const float*)d_in[10],  // ab2
        (const float*)d_in[11],  // mw1
        (const float*)d_in[12],  // mb1
        (const float*)d_in[13],  // mw2
        (const float*)d_in[14],  // mb2
        (const float*)d_in[15],  // mw3
        (const float*)d_in[16],  // mb3
        ws,
        (float*)d_out);
}